// Round 7
// baseline (198.587 us; speedup 1.0000x reference)
//
#include <hip/hip_runtime.h>
#include <math.h>

// FocalLoss fused single-kernel: per-anchor nearest-annotation argmin
// (squared-distance space; sqrt is monotone so min matches reference) +
// focal / smooth-L1 terms, 4 anchors/thread, block partials in d_ws,
// last-finished block (device-scope counter) reduces partials -> 3 outputs.
// Arithmetic identical to the round-5 2-kernel version (passed, absmax=0.0).
// Counter zeroed by a tiny kernel (no hipMemsetAsync -> zero graph-capture risk).

constexpr int B_   = 4;
constexpr int N_   = 262144;
constexpr int C_   = 4;
constexpr int M_   = 64;
constexpr int TPB  = 256;
constexpr int APT  = 4;                 // anchors per thread
constexpr int TILE = TPB * APT;         // 1024 anchors per block
constexpr int BPI  = N_ / TILE;         // 256 blocks per image (== TPB)
constexpr int NBLK = BPI * B_;          // 1024 total blocks

__global__ void zero_counter(int* __restrict__ counter) {
    *counter = 0;
}

__global__ __launch_bounds__(TPB) void focal_fused(
    const float* __restrict__ cls,   // (B,N,C)
    const float* __restrict__ reg,   // (B,N,3)
    const float* __restrict__ anc,   // (B,N,3) -- reference uses anchors[0]
    const float* __restrict__ ann,   // (B,M,5) [gx, gy, gal, label, status]
    float4* __restrict__ part,       // (B, BPI) partials {cls, xy, ang, npos}
    int*    __restrict__ counter,    // zeroed by zero_counter each launch
    float*  __restrict__ out)        // 3 scalars
{
    const int bx   = blockIdx.x;
    const int b    = blockIdx.y;
    const int tid  = threadIdx.x;
    const int base = bx * TILE + tid;   // anchor k: base + k*TPB

    __shared__ float2 s_gxy[M_];   // invalid -> (1e30,1e30): d2 = inf, never argmin
    __shared__ float  s_al[M_];
    __shared__ float  s_lab[M_];

    if (tid < M_) {
        const float* a5 = ann + ((size_t)b * M_ + tid) * 5;
        float gx = a5[0], gy = a5[1], gal = a5[2], lab = a5[3];
        bool valid = (lab != -1.0f);
        s_gxy[tid] = make_float2(valid ? gx : 1e30f, valid ? gy : 1e30f);
        s_al[tid]  = gal;
        s_lab[tid] = lab;
    }
    __syncthreads();

    // ---- load 4 anchors (b=0 slice, as in reference) ----
    float ax[APT], ay[APT], aal[APT];
    #pragma unroll
    for (int k = 0; k < APT; ++k) {
        const float* a3 = anc + (size_t)(base + k * TPB) * 3;
        ax[k] = a3[0]; ay[k] = a3[1]; aal[k] = a3[2];
    }

    // ---- joint argmin over M annotations, 4 anchors in flight ----
    float bestd2[APT];
    int   bestj[APT];
    #pragma unroll
    for (int k = 0; k < APT; ++k) { bestd2[k] = __builtin_inff(); bestj[k] = 0; }

    #pragma unroll 8
    for (int j = 0; j < M_; ++j) {
        const float2 g = s_gxy[j];          // uniform address -> LDS broadcast
        #pragma unroll
        for (int k = 0; k < APT; ++k) {
            float dx = ax[k] - g.x;
            float dy = ay[k] - g.y;
            float d2 = fmaf(dy, dy, dx * dx);
            if (d2 < bestd2[k]) { bestd2[k] = d2; bestj[k] = j; }  // strict < == first idx
        }
    }

    // ---- per-anchor epilogue, accumulated across k ----
    float cls_s = 0.0f, xy_s = 0.0f, ang_s = 0.0f, npos = 0.0f;
    #pragma unroll
    for (int k = 0; k < APT; ++k) {
        const int   i    = base + k * TPB;
        const float best = sqrtf(bestd2[k]);     // == reference dxy_min (monotone)
        const float2 gb  = s_gxy[bestj[k]];
        const float gal  = s_al[bestj[k]];
        const float lab  = s_lab[bestj[k]];
        const float a    = fabsf(aal[k] - gal);

        const bool pos  = (best <= 10.0f) && (a <= 15.0f) && (lab != -1.0f);
        const bool farr = (best >= 15.0f) || (a >= 22.5f);
        npos += pos ? 1.0f : 0.0f;

        if (pos || farr) {
            const float4 p4 = *reinterpret_cast<const float4*>(cls + ((size_t)b * N_ + i) * C_);
            const float p[4] = {p4.x, p4.y, p4.z, p4.w};
            const int li = pos ? (int)fminf(fmaxf(lab, 0.0f), 3.0f) : -1;
            #pragma unroll
            for (int c = 0; c < 4; ++c) {
                float pc  = fminf(fmaxf(p[c], 1e-4f), 0.9999f);
                bool  is1 = (c == li);
                float af  = is1 ? 0.95f : 0.05f;
                float w   = is1 ? (1.0f - pc) : pc;
                float arg = is1 ? pc : (1.0f - pc);
                cls_s += af * w * w * (-__logf(arg));
            }
        }

        if (pos) {
            const float* r3 = reg + ((size_t)b * N_ + i) * 3;
            const float rx = r3[0], ry = r3[1], ral = r3[2];
            const float tx = gb.x - ax[k], ty = gb.y - ay[k], tal = gal - aal[k];
            const float d1 = fabsf(tx - rx);
            const float d2 = fabsf(ty - ry);
            const float beta = 1.0f / 9.0f;
            const float s1 = (d1 <= beta) ? 4.5f * d1 * d1 : d1 - (0.5f / 9.0f);
            const float s2 = (d2 <= beta) ? 4.5f * d2 * d2 : d2 - (0.5f / 9.0f);
            xy_s += s1 + s2;
            const float da = (fabsf(tal - ral) - 10.0f) / 5.0f;
            ang_s += fmaxf(da, 0.0f);
        }
    }

    // ---- block reduction: 4 waves -> float4 partial ----
    float v0 = cls_s, v1 = xy_s, v2 = ang_s, v3 = npos;
    #pragma unroll
    for (int off = 32; off; off >>= 1) {
        v0 += __shfl_down(v0, off, 64);
        v1 += __shfl_down(v1, off, 64);
        v2 += __shfl_down(v2, off, 64);
        v3 += __shfl_down(v3, off, 64);
    }
    __shared__ float4 s_red[TPB / 64];
    const int lane = tid & 63, wid = tid >> 6;
    if (lane == 0) s_red[wid] = make_float4(v0, v1, v2, v3);
    __syncthreads();
    if (tid == 0) {
        float4 acc = s_red[0];
        #pragma unroll
        for (int w = 1; w < TPB / 64; ++w) {
            acc.x += s_red[w].x; acc.y += s_red[w].y;
            acc.z += s_red[w].z; acc.w += s_red[w].w;
        }
        part[(size_t)b * BPI + bx] = acc;
    }

    // ---- last-block-done detection (device scope, cross-XCD safe) ----
    __shared__ bool s_last;
    __threadfence();                      // release partial stores (agent scope)
    if (tid == 0) {
        int old = __hip_atomic_fetch_add(counter, 1, __ATOMIC_ACQ_REL,
                                         __HIP_MEMORY_SCOPE_AGENT);
        s_last = (old == NBLK - 1);
    }
    __syncthreads();
    if (!s_last) return;

    // ---- finalize (exactly the round-5 finalize arithmetic) ----
    __threadfence();                      // acquire: see all blocks' partials
    __shared__ float4 s_red2[TPB / 64];
    float cm = 0.0f, xm = 0.0f, am = 0.0f;

    for (int b2 = 0; b2 < B_; ++b2) {
        float4 p = part[(size_t)b2 * BPI + tid];   // BPI == TPB: 1 read/thread
        float c = p.x, x = p.y, g = p.z, n = p.w;
        #pragma unroll
        for (int off = 32; off; off >>= 1) {
            c += __shfl_down(c, off, 64);
            x += __shfl_down(x, off, 64);
            g += __shfl_down(g, off, 64);
            n += __shfl_down(n, off, 64);
        }
        __syncthreads();                  // protect s_red2 from previous iter
        if (lane == 0) s_red2[wid] = make_float4(c, x, g, n);
        __syncthreads();
        if (tid == 0) {
            float4 acc = s_red2[0];
            #pragma unroll
            for (int w = 1; w < TPB / 64; ++w) {
                acc.x += s_red2[w].x; acc.y += s_red2[w].y;
                acc.z += s_red2[w].z; acc.w += s_red2[w].w;
            }
            const float npf = fmaxf(acc.w, 1.0f);
            const float has = (acc.w > 0.0f) ? 1.0f : 0.0f;
            cm += acc.x / npf;
            xm += acc.y / (2.0f * npf) * has;
            am += acc.z / npf * has;
        }
    }
    if (tid == 0) {
        out[0] = cm * 0.25f;
        out[1] = xm * 0.25f;
        out[2] = am * 0.25f;
    }
}

extern "C" void kernel_launch(void* const* d_in, const int* in_sizes, int n_in,
                              void* d_out, int out_size, void* d_ws, size_t ws_size,
                              hipStream_t stream)
{
    const float* cls = (const float*)d_in[0];   // classifications (B,N,C)
    const float* reg = (const float*)d_in[1];   // regressions    (B,N,3)
    const float* anc = (const float*)d_in[2];   // anchors        (B,N,3)
    const float* ann = (const float*)d_in[3];   // annotations    (B,M,5)

    int*    counter = (int*)d_ws;                         // [0,64): counter
    float4* part    = (float4*)((char*)d_ws + 64);        // 16 KB partials

    zero_counter<<<1, 1, 0, stream>>>(counter);           // graph-safe init
    focal_fused<<<dim3(BPI, B_), TPB, 0, stream>>>(cls, reg, anc, ann,
                                                   part, counter, (float*)d_out);
}

// Round 15
// 95.735 us; speedup vs baseline: 2.0744x; 2.0744x over previous
//
#include <hip/hip_runtime.h>
#include <math.h>

// FocalLoss, 2-kernel structure (round-5 form: passed, absmax=0.0).
// cls float4 loads issued BEFORE the argmin loop; keep-alive asm placed
// AFTER the loop so s_waitcnt lands post-loop (latency hidden under the
// 64-iter argmin), while keeping p4 unconditionally live so the loads
// can't be sunk into the pos||farr branch (round-7 codegen, VGPR=24).
// All arithmetic and reduction orders bit-identical to round 5.
// Fused variant REGRESSED (round 7: 198 vs 95 us) -- threadfence + 1024
// same-address device atomics serialized ~100us. Do not re-fuse.

constexpr int B_   = 4;
constexpr int N_   = 262144;
constexpr int C_   = 4;
constexpr int M_   = 64;
constexpr int TPB  = 256;
constexpr int APT  = 4;                 // anchors per thread
constexpr int TILE = TPB * APT;         // 1024 anchors per block
constexpr int BPI  = N_ / TILE;         // 256 blocks per image (== TPB)

__global__ __launch_bounds__(TPB) void focal_main(
    const float* __restrict__ cls,   // (B,N,C)
    const float* __restrict__ reg,   // (B,N,3)
    const float* __restrict__ anc,   // (B,N,3) -- reference uses anchors[0]
    const float* __restrict__ ann,   // (B,M,5) [gx, gy, gal, label, status]
    float4* __restrict__ part)       // (B, BPI) partials {cls, xy, ang, npos}
{
    const int bx   = blockIdx.x;
    const int b    = blockIdx.y;
    const int tid  = threadIdx.x;
    const int base = bx * TILE + tid;   // anchor k: base + k*TPB

    __shared__ float2 s_gxy[M_];   // invalid -> (1e30,1e30): d2 = inf, never argmin
    __shared__ float  s_al[M_];
    __shared__ float  s_lab[M_];

    if (tid < M_) {
        const float* a5 = ann + ((size_t)b * M_ + tid) * 5;
        float gx = a5[0], gy = a5[1], gal = a5[2], lab = a5[3];
        bool valid = (lab != -1.0f);
        s_gxy[tid] = make_float2(valid ? gx : 1e30f, valid ? gy : 1e30f);
        s_al[tid]  = gal;
        s_lab[tid] = lab;
    }
    __syncthreads();

    // ---- load 4 anchors (b=0 slice, as in reference) ----
    float ax[APT], ay[APT], aal[APT];
    #pragma unroll
    for (int k = 0; k < APT; ++k) {
        const float* a3 = anc + (size_t)(base + k * TPB) * 3;
        ax[k] = a3[0]; ay[k] = a3[1]; aal[k] = a3[2];
    }

    // ---- issue cls loads pre-loop (latency hides under argmin loop) ----
    float4 p4[APT];
    #pragma unroll
    for (int k = 0; k < APT; ++k)
        p4[k] = *reinterpret_cast<const float4*>(cls + ((size_t)b * N_ + (base + k * TPB)) * C_);

    // ---- joint argmin over M annotations, 4 anchors in flight ----
    float bestd2[APT];
    int   bestj[APT];
    #pragma unroll
    for (int k = 0; k < APT; ++k) { bestd2[k] = __builtin_inff(); bestj[k] = 0; }

    #pragma unroll 8
    for (int j = 0; j < M_; ++j) {
        const float2 g = s_gxy[j];          // uniform address -> LDS broadcast
        #pragma unroll
        for (int k = 0; k < APT; ++k) {
            float dx = ax[k] - g.x;
            float dy = ay[k] - g.y;
            float d2 = fmaf(dy, dy, dx * dx);
            if (d2 < bestd2[k]) { bestd2[k] = d2; bestj[k] = j; }  // strict < == first idx
        }
    }

    // keep-alive AFTER the loop: forces unconditional post-loop liveness of
    // p4 (no sink into the pos||farr branch); s_waitcnt lands here, latency
    // already covered by the 64-iteration loop above.
    #pragma unroll
    for (int k = 0; k < APT; ++k)
        asm volatile("" :: "v"(p4[k].x), "v"(p4[k].y), "v"(p4[k].z), "v"(p4[k].w));

    // ---- per-anchor epilogue, accumulated across k (order == round 5) ----
    float cls_s = 0.0f, xy_s = 0.0f, ang_s = 0.0f, npos = 0.0f;
    #pragma unroll
    for (int k = 0; k < APT; ++k) {
        const int   i    = base + k * TPB;
        const float best = sqrtf(bestd2[k]);     // == reference dxy_min (monotone)
        const float2 gb  = s_gxy[bestj[k]];
        const float gal  = s_al[bestj[k]];
        const float lab  = s_lab[bestj[k]];
        const float a    = fabsf(aal[k] - gal);

        const bool pos  = (best <= 10.0f) && (a <= 15.0f) && (lab != -1.0f);
        const bool farr = (best >= 15.0f) || (a >= 22.5f);
        npos += pos ? 1.0f : 0.0f;

        if (pos || farr) {
            const float p[4] = {p4[k].x, p4[k].y, p4[k].z, p4[k].w};
            const int li = pos ? (int)fminf(fmaxf(lab, 0.0f), 3.0f) : -1;
            #pragma unroll
            for (int c = 0; c < 4; ++c) {
                float pc  = fminf(fmaxf(p[c], 1e-4f), 0.9999f);
                bool  is1 = (c == li);
                float af  = is1 ? 0.95f : 0.05f;
                float w   = is1 ? (1.0f - pc) : pc;
                float arg = is1 ? pc : (1.0f - pc);
                cls_s += af * w * w * (-__logf(arg));
            }
        }

        if (pos) {   // ~1e-6 of anchors: exec-masked, loads rarely issue
            const float* r3 = reg + ((size_t)b * N_ + i) * 3;
            const float rx = r3[0], ry = r3[1], ral = r3[2];
            const float tx = gb.x - ax[k], ty = gb.y - ay[k], tal = gal - aal[k];
            const float d1 = fabsf(tx - rx);
            const float d2 = fabsf(ty - ry);
            const float beta = 1.0f / 9.0f;
            const float s1 = (d1 <= beta) ? 4.5f * d1 * d1 : d1 - (0.5f / 9.0f);
            const float s2 = (d2 <= beta) ? 4.5f * d2 * d2 : d2 - (0.5f / 9.0f);
            xy_s += s1 + s2;
            const float da = (fabsf(tal - ral) - 10.0f) / 5.0f;
            ang_s += fmaxf(da, 0.0f);
        }
    }

    // ---- block reduction: 4 waves -> float4 partial (order == round 5) ----
    float v0 = cls_s, v1 = xy_s, v2 = ang_s, v3 = npos;
    #pragma unroll
    for (int off = 32; off; off >>= 1) {
        v0 += __shfl_down(v0, off, 64);
        v1 += __shfl_down(v1, off, 64);
        v2 += __shfl_down(v2, off, 64);
        v3 += __shfl_down(v3, off, 64);
    }
    __shared__ float4 s_red[TPB / 64];
    const int lane = tid & 63, wid = tid >> 6;
    if (lane == 0) s_red[wid] = make_float4(v0, v1, v2, v3);
    __syncthreads();
    if (tid == 0) {
        float4 acc = s_red[0];
        #pragma unroll
        for (int w = 1; w < TPB / 64; ++w) {
            acc.x += s_red[w].x; acc.y += s_red[w].y;
            acc.z += s_red[w].z; acc.w += s_red[w].w;
        }
        part[(size_t)b * BPI + bx] = acc;
    }
}

__global__ __launch_bounds__(256) void focal_final(
    const float4* __restrict__ part, float* __restrict__ out)
{
    const int tid  = threadIdx.x;
    const int lane = tid & 63, wid = tid >> 6;
    __shared__ float4 s_red[4];
    float cm = 0.0f, xm = 0.0f, am = 0.0f;

    for (int b = 0; b < B_; ++b) {
        float c = 0.0f, x = 0.0f, g = 0.0f, n = 0.0f;
        for (int k = tid; k < BPI; k += 256) {   // BPI==256: exactly 1 iter
            float4 p = part[(size_t)b * BPI + k];
            c += p.x; x += p.y; g += p.z; n += p.w;
        }
        #pragma unroll
        for (int off = 32; off; off >>= 1) {
            c += __shfl_down(c, off, 64);
            x += __shfl_down(x, off, 64);
            g += __shfl_down(g, off, 64);
            n += __shfl_down(n, off, 64);
        }
        __syncthreads();
        if (lane == 0) s_red[wid] = make_float4(c, x, g, n);
        __syncthreads();
        if (tid == 0) {
            float4 acc = s_red[0];
            #pragma unroll
            for (int w = 1; w < 4; ++w) {
                acc.x += s_red[w].x; acc.y += s_red[w].y;
                acc.z += s_red[w].z; acc.w += s_red[w].w;
            }
            const float npf = fmaxf(acc.w, 1.0f);
            const float has = (acc.w > 0.0f) ? 1.0f : 0.0f;
            cm += acc.x / npf;
            xm += acc.y / (2.0f * npf) * has;
            am += acc.z / npf * has;
        }
    }
    if (tid == 0) {
        out[0] = cm * 0.25f;
        out[1] = xm * 0.25f;
        out[2] = am * 0.25f;
    }
}

extern "C" void kernel_launch(void* const* d_in, const int* in_sizes, int n_in,
                              void* d_out, int out_size, void* d_ws, size_t ws_size,
                              hipStream_t stream)
{
    const float* cls = (const float*)d_in[0];   // classifications (B,N,C)
    const float* reg = (const float*)d_in[1];   // regressions    (B,N,3)
    const float* anc = (const float*)d_in[2];   // anchors        (B,N,3)
    const float* ann = (const float*)d_in[3];   // annotations    (B,M,5)
    float4* part = (float4*)d_ws;               // 4*256*16 B = 16 KB scratch

    focal_main<<<dim3(BPI, B_), TPB, 0, stream>>>(cls, reg, anc, ann, part);
    focal_final<<<1, 256, 0, stream>>>(part, (float*)d_out);
}

// Round 16
// 93.416 us; speedup vs baseline: 2.1258x; 1.0248x over previous
//
#include <hip/hip_runtime.h>
#include <math.h>

// FocalLoss, 2-kernel structure. Round-16 change: APT 4->2 (TILE=512, 2048
// blocks = 8 blocks/CU = 32 waves/CU, was 16) to test the occupancy-limited
// latency-hiding hypothesis: R15 showed cls-prefetch neutral (95.7 vs 94.9)
// and ~30us controllable kernel time vs ~7us modeled VALU work at 4 waves/SIMD.
// Summation order changes (BPI=512): expected absmax ~1e-4 absolute (first
// nonzero), relative ~1e-6 -- inside validator threshold.
// Known: harness floor ~65us in-window (43us d_ws poison-fill + restore+gaps).
// Fused variant REGRESSED (R7: 198 vs 95us) -- do not re-fuse.

constexpr int B_   = 4;
constexpr int N_   = 262144;
constexpr int C_   = 4;
constexpr int M_   = 64;
constexpr int TPB  = 256;
constexpr int APT  = 2;                 // anchors per thread (was 4)
constexpr int TILE = TPB * APT;         // 512 anchors per block
constexpr int BPI  = N_ / TILE;         // 512 blocks per image

__global__ __launch_bounds__(TPB) void focal_main(
    const float* __restrict__ cls,   // (B,N,C)
    const float* __restrict__ reg,   // (B,N,3)
    const float* __restrict__ anc,   // (B,N,3) -- reference uses anchors[0]
    const float* __restrict__ ann,   // (B,M,5) [gx, gy, gal, label, status]
    float4* __restrict__ part)       // (B, BPI) partials {cls, xy, ang, npos}
{
    const int bx   = blockIdx.x;
    const int b    = blockIdx.y;
    const int tid  = threadIdx.x;
    const int base = bx * TILE + tid;   // anchor k: base + k*TPB

    __shared__ float2 s_gxy[M_];   // invalid -> (1e30,1e30): d2 = inf, never argmin
    __shared__ float  s_al[M_];
    __shared__ float  s_lab[M_];

    if (tid < M_) {
        const float* a5 = ann + ((size_t)b * M_ + tid) * 5;
        float gx = a5[0], gy = a5[1], gal = a5[2], lab = a5[3];
        bool valid = (lab != -1.0f);
        s_gxy[tid] = make_float2(valid ? gx : 1e30f, valid ? gy : 1e30f);
        s_al[tid]  = gal;
        s_lab[tid] = lab;
    }
    __syncthreads();

    // ---- load anchors (b=0 slice, as in reference) ----
    float ax[APT], ay[APT], aal[APT];
    #pragma unroll
    for (int k = 0; k < APT; ++k) {
        const float* a3 = anc + (size_t)(base + k * TPB) * 3;
        ax[k] = a3[0]; ay[k] = a3[1]; aal[k] = a3[2];
    }

    // ---- issue cls loads pre-loop (latency hides under argmin loop) ----
    float4 p4[APT];
    #pragma unroll
    for (int k = 0; k < APT; ++k)
        p4[k] = *reinterpret_cast<const float4*>(cls + ((size_t)b * N_ + (base + k * TPB)) * C_);

    // ---- joint argmin over M annotations, APT anchors in flight ----
    float bestd2[APT];
    int   bestj[APT];
    #pragma unroll
    for (int k = 0; k < APT; ++k) { bestd2[k] = __builtin_inff(); bestj[k] = 0; }

    #pragma unroll 8
    for (int j = 0; j < M_; ++j) {
        const float2 g = s_gxy[j];          // uniform address -> LDS broadcast
        #pragma unroll
        for (int k = 0; k < APT; ++k) {
            float dx = ax[k] - g.x;
            float dy = ay[k] - g.y;
            float d2 = fmaf(dy, dy, dx * dx);
            if (d2 < bestd2[k]) { bestd2[k] = d2; bestj[k] = j; }  // strict < == first idx
        }
    }

    // keep-alive AFTER the loop: p4 unconditionally live (no sink into the
    // pos||farr branch); vmcnt wait lands here, latency covered by the loop.
    #pragma unroll
    for (int k = 0; k < APT; ++k)
        asm volatile("" :: "v"(p4[k].x), "v"(p4[k].y), "v"(p4[k].z), "v"(p4[k].w));

    // ---- per-anchor epilogue, accumulated across k ----
    float cls_s = 0.0f, xy_s = 0.0f, ang_s = 0.0f, npos = 0.0f;
    #pragma unroll
    for (int k = 0; k < APT; ++k) {
        const int   i    = base + k * TPB;
        const float best = sqrtf(bestd2[k]);     // == reference dxy_min (monotone)
        const float2 gb  = s_gxy[bestj[k]];
        const float gal  = s_al[bestj[k]];
        const float lab  = s_lab[bestj[k]];
        const float a    = fabsf(aal[k] - gal);

        const bool pos  = (best <= 10.0f) && (a <= 15.0f) && (lab != -1.0f);
        const bool farr = (best >= 15.0f) || (a >= 22.5f);
        npos += pos ? 1.0f : 0.0f;

        if (pos || farr) {
            const float p[4] = {p4[k].x, p4[k].y, p4[k].z, p4[k].w};
            const int li = pos ? (int)fminf(fmaxf(lab, 0.0f), 3.0f) : -1;
            #pragma unroll
            for (int c = 0; c < 4; ++c) {
                float pc  = fminf(fmaxf(p[c], 1e-4f), 0.9999f);
                bool  is1 = (c == li);
                float af  = is1 ? 0.95f : 0.05f;
                float w   = is1 ? (1.0f - pc) : pc;
                float arg = is1 ? pc : (1.0f - pc);
                cls_s += af * w * w * (-__logf(arg));
            }
        }

        if (pos) {   // rare: exec-masked, loads rarely issue
            const float* r3 = reg + ((size_t)b * N_ + i) * 3;
            const float rx = r3[0], ry = r3[1], ral = r3[2];
            const float tx = gb.x - ax[k], ty = gb.y - ay[k], tal = gal - aal[k];
            const float d1 = fabsf(tx - rx);
            const float d2 = fabsf(ty - ry);
            const float beta = 1.0f / 9.0f;
            const float s1 = (d1 <= beta) ? 4.5f * d1 * d1 : d1 - (0.5f / 9.0f);
            const float s2 = (d2 <= beta) ? 4.5f * d2 * d2 : d2 - (0.5f / 9.0f);
            xy_s += s1 + s2;
            const float da = (fabsf(tal - ral) - 10.0f) / 5.0f;
            ang_s += fmaxf(da, 0.0f);
        }
    }

    // ---- block reduction: 4 waves -> float4 partial ----
    float v0 = cls_s, v1 = xy_s, v2 = ang_s, v3 = npos;
    #pragma unroll
    for (int off = 32; off; off >>= 1) {
        v0 += __shfl_down(v0, off, 64);
        v1 += __shfl_down(v1, off, 64);
        v2 += __shfl_down(v2, off, 64);
        v3 += __shfl_down(v3, off, 64);
    }
    __shared__ float4 s_red[TPB / 64];
    const int lane = tid & 63, wid = tid >> 6;
    if (lane == 0) s_red[wid] = make_float4(v0, v1, v2, v3);
    __syncthreads();
    if (tid == 0) {
        float4 acc = s_red[0];
        #pragma unroll
        for (int w = 1; w < TPB / 64; ++w) {
            acc.x += s_red[w].x; acc.y += s_red[w].y;
            acc.z += s_red[w].z; acc.w += s_red[w].w;
        }
        part[(size_t)b * BPI + bx] = acc;
    }
}

__global__ __launch_bounds__(256) void focal_final(
    const float4* __restrict__ part, float* __restrict__ out)
{
    const int tid  = threadIdx.x;
    const int lane = tid & 63, wid = tid >> 6;
    __shared__ float4 s_red[4];
    float cm = 0.0f, xm = 0.0f, am = 0.0f;

    for (int b = 0; b < B_; ++b) {
        float c = 0.0f, x = 0.0f, g = 0.0f, n = 0.0f;
        for (int k = tid; k < BPI; k += 256) {   // BPI=512: 2 iters
            float4 p = part[(size_t)b * BPI + k];
            c += p.x; x += p.y; g += p.z; n += p.w;
        }
        #pragma unroll
        for (int off = 32; off; off >>= 1) {
            c += __shfl_down(c, off, 64);
            x += __shfl_down(x, off, 64);
            g += __shfl_down(g, off, 64);
            n += __shfl_down(n, off, 64);
        }
        __syncthreads();
        if (lane == 0) s_red[wid] = make_float4(c, x, g, n);
        __syncthreads();
        if (tid == 0) {
            float4 acc = s_red[0];
            #pragma unroll
            for (int w = 1; w < 4; ++w) {
                acc.x += s_red[w].x; acc.y += s_red[w].y;
                acc.z += s_red[w].z; acc.w += s_red[w].w;
            }
            const float npf = fmaxf(acc.w, 1.0f);
            const float has = (acc.w > 0.0f) ? 1.0f : 0.0f;
            cm += acc.x / npf;
            xm += acc.y / (2.0f * npf) * has;
            am += acc.z / npf * has;
        }
    }
    if (tid == 0) {
        out[0] = cm * 0.25f;
        out[1] = xm * 0.25f;
        out[2] = am * 0.25f;
    }
}

extern "C" void kernel_launch(void* const* d_in, const int* in_sizes, int n_in,
                              void* d_out, int out_size, void* d_ws, size_t ws_size,
                              hipStream_t stream)
{
    const float* cls = (const float*)d_in[0];   // classifications (B,N,C)
    const float* reg = (const float*)d_in[1];   // regressions    (B,N,3)
    const float* anc = (const float*)d_in[2];   // anchors        (B,N,3)
    const float* ann = (const float*)d_in[3];   // annotations    (B,M,5)
    float4* part = (float4*)d_ws;               // 4*512*16 B = 32 KB scratch

    focal_main<<<dim3(BPI, B_), TPB, 0, stream>>>(cls, reg, anc, ann, part);
    focal_final<<<1, 256, 0, stream>>>(part, (float*)d_out);
}